// Round 3
// baseline (1673.287 us; speedup 1.0000x reference)
//
#include <hip/hip_runtime.h>
#include <hip/hip_bf16.h>
#include <stdint.h>

// ---------------------------------------------------------------------------
// Pipeline:
//  K1 build_bpk : W_bl1 [97,194,194] f32 -> Bpk bf16, MFMA b-frag layout
//                 [i=194][ks=7][t=7][lane=64][m=8] (j pad 194->224, k pad
//                 97->112), 9,734,144 bytes (194*7*7*64 short8).
//  K2 proj      : proj = n @ W_bl[0]  [65536,97] f32.
//  K3 score     : s = dot(proj[dst], e); atomicMax segment max (monotone key).
//  K4 accum     : ex = exp(s-max); atomicAdd denom + numerator rel[dst]
//                 (rel stride 200 f32).
//  K5 dinv      : denom -> reciprocal in place (0 for empty segments).
//  K6 gate      : per 128-edge block stage s=rel[src]*dinv, d=rel[dst]*dinv
//                 as bf16 in LDS; gate[e,k] = sum_ij s_i W[k,i,j] d_j via
//                 mfma_f32_16x16x32_bf16 (A formed on the fly:
//                 A[e, i*224+j] = s_i*d_j); epilogue out = e*(1+sigmoid).
//
// ws layout (bytes) — total 63,475,712:
//  region A @ 0        52,428,800   proj [N,97] f32 first, then rel [N,200] f32
//                                   (proj dead after K3; memset between)
//  Bpk     @ 52428800   9,736,192   (9,734,144 used; FIXED: was 9,732,096 and
//                                    build_bpk's tail clobbered s_buf -> gate
//                                    read score bytes as B-frags for k=80..96)
//  s_buf   @ 62164992     262,144
//  smax    @ 62427136     524,288
//  denom   @ 62951424     524,288
// ---------------------------------------------------------------------------

typedef __attribute__((ext_vector_type(8))) short short8;
typedef __attribute__((ext_vector_type(4))) float f32x4;
typedef __attribute__((ext_vector_type(4))) unsigned int u32x4;

#define NN 65536      // nodes
#define NE1 32768     // edges per etype
#define NEG 65536     // edges total
#define DC 768
#define DR 97
#define DR2 194
#define RELSTR 200    // rel row stride (f32)
#define SSTR 208      // s_lds row stride (ushorts)
#define DSTR 232      // d_lds row stride (ushorts)
#define KI 194
#define KS 7          // j k-steps of 32 (194 -> 224)
#define NT 7          // n tiles of 16 (97 -> 112)

#define OFF_REL   0ull
#define OFF_BPK   52428800ull
#define OFF_SBUF  62164992ull
#define OFF_SMAX  62427136ull
#define OFF_DEN   62951424ull

static __device__ __forceinline__ float bf2f(unsigned short u) {
    return __uint_as_float(((unsigned)u) << 16);
}
static __device__ __forceinline__ unsigned short f2bf(float f) {
    return __builtin_bit_cast(unsigned short, __float2bfloat16(f));
}
// monotone float->uint key for atomicMax over signed floats (0 = "empty")
static __device__ __forceinline__ unsigned fkey(float f) {
    unsigned b = __float_as_uint(f);
    return (b & 0x80000000u) ? ~b : (b | 0x80000000u);
}
static __device__ __forceinline__ float funkey(unsigned k) {
    return __uint_as_float((k & 0x80000000u) ? (k & 0x7fffffffu) : ~k);
}

// ---------------- K1: W_bl1 -> Bpk (b-frag-packed bf16) --------------------
__global__ void build_bpk(const float* __restrict__ W, unsigned short* __restrict__ Bpk) {
    int id = blockIdx.x * blockDim.x + threadIdx.x;  // ((i*7+ks)*7+t)*64 + l
    const int total = KI * KS * NT * 64;
    if (id >= total) return;
    int l = id & 63;
    int g = id >> 6;
    int t = g % NT;
    int ks = (g / NT) % KS;
    int i = g / (NT * KS);
    int kk = t * 16 + (l & 15);
    int jb = ks * 32 + (l >> 4) * 8;
    short8 pk;
#pragma unroll
    for (int m = 0; m < 8; ++m) {
        int j = jb + m;
        float f = (kk < DR && j < DR2) ? W[(size_t)kk * (DR2 * DR2) + i * DR2 + j] : 0.f;
        pk[m] = (short)f2bf(f);
    }
    *(short8*)(Bpk + (size_t)id * 8) = pk;
}

// ---------------- K2: proj = n @ W_bl ---------------------------------------
__global__ void proj_kernel(const float* __restrict__ nmat, const float* __restrict__ Wb,
                            float* __restrict__ proj) {
    __shared__ float tile[32][128];
    int tid = threadIdx.x;            // 128 threads
    int r0 = blockIdx.x * 32;
    float acc[32];
#pragma unroll
    for (int j = 0; j < 32; ++j) acc[j] = 0.f;
    for (int i0 = 0; i0 < DC; i0 += 128) {
#pragma unroll
        for (int q = 0; q < 32; ++q)
            tile[q][tid] = nmat[(size_t)(r0 + q) * DC + i0 + tid];
        __syncthreads();
        if (tid < DR) {
            const float* wp = Wb + (size_t)i0 * DR + tid;
            for (int ii = 0; ii < 128; ++ii) {
                float w = wp[(size_t)ii * DR];
#pragma unroll
                for (int j = 0; j < 32; ++j) acc[j] += tile[j][ii] * w;
            }
        }
        __syncthreads();
    }
    if (tid < DR) {
#pragma unroll
        for (int j = 0; j < 32; ++j) proj[(size_t)(r0 + j) * DR + tid] = acc[j];
    }
}

// ---------------- K3: per-edge score + segment max --------------------------
__global__ void score_kernel(const float* __restrict__ proj,
                             const float* __restrict__ e_inter, const float* __restrict__ e_intra,
                             const int* __restrict__ dst_inter, const int* __restrict__ dst_intra,
                             float* __restrict__ s_buf, unsigned* __restrict__ smax_key) {
    int wid = (blockIdx.x * blockDim.x + threadIdx.x) >> 6;
    int lane = threadIdx.x & 63;
    if (wid >= NEG) return;
    int et = wid >> 15, le = wid & (NE1 - 1);
    const float* e = (et ? e_intra : e_inter) + (size_t)le * DR;
    int dst = (et ? dst_intra : dst_inter)[le];
    const float* pr = proj + (size_t)dst * DR;
    float p = pr[lane] * e[lane];
    if (lane < DR - 64) p += pr[lane + 64] * e[lane + 64];
#pragma unroll
    for (int off = 32; off > 0; off >>= 1) p += __shfl_down(p, off);
    if (lane == 0) {
        s_buf[wid] = p;
        atomicMax(&smax_key[et * NN + dst], fkey(p));
    }
}

// ---------------- K4: exp + segment sums ------------------------------------
__global__ void accum_kernel(const float* __restrict__ s_buf,
                             const float* __restrict__ e_inter, const float* __restrict__ e_intra,
                             const int* __restrict__ dst_inter, const int* __restrict__ dst_intra,
                             const unsigned* __restrict__ smax_key,
                             float* __restrict__ denom, float* __restrict__ rel) {
    int wid = (blockIdx.x * blockDim.x + threadIdx.x) >> 6;
    int lane = threadIdx.x & 63;
    if (wid >= NEG) return;
    int et = wid >> 15, le = wid & (NE1 - 1);
    const float* e = (et ? e_intra : e_inter) + (size_t)le * DR;
    int dst = (et ? dst_intra : dst_inter)[le];
    float s = s_buf[wid];
    float mx = funkey(smax_key[et * NN + dst]);
    float ex = __expf(s - mx);
    if (lane == 0) atomicAdd(&denom[et * NN + dst], ex);
    float* rrow = rel + (size_t)dst * RELSTR + et * DR;
    atomicAdd(&rrow[lane], e[lane] * ex);
    if (lane < DR - 64) atomicAdd(&rrow[lane + 64], e[lane + 64] * ex);
}

// ---------------- K5: denom -> 1/denom (0 if empty) -------------------------
__global__ void dinv_kernel(float* __restrict__ denom) {
    int i = blockIdx.x * blockDim.x + threadIdx.x;
    if (i < 2 * NN) {
        float d = denom[i];
        denom[i] = (d > 0.f) ? (1.f / d) : 0.f;
    }
}

// ---------------- K6: bilinear gate via MFMA --------------------------------
__launch_bounds__(512, 1)
__global__ void gate_kernel(const float* __restrict__ rel, const float* __restrict__ dinv,
                            const unsigned short* __restrict__ Bpk,
                            const float* __restrict__ bias,
                            const int* __restrict__ src_inter, const int* __restrict__ dst_inter,
                            const int* __restrict__ src_intra, const int* __restrict__ dst_intra,
                            const float* __restrict__ e_inter, const float* __restrict__ e_intra,
                            float* __restrict__ out) {
    __shared__ unsigned short s_lds[128][SSTR];   // 53,248 B
    __shared__ unsigned short d_lds[128][DSTR];   // 59,392 B
    int tid = threadIdx.x;                        // 512
    int blk = blockIdx.x;                         // 512 blocks
    int ebase = blk << 7;                         // 128 edges/block
    int et = ebase >> 15;                         // uniform per block
    const int* srcp = et ? src_intra : src_inter;
    const int* dstp = et ? dst_intra : dst_inter;
    const float* ep = et ? e_intra : e_inter;
    int lbase = ebase & (NE1 - 1);

    // ---- gather rel rows (x dinv, -> bf16) for 128 edges ----
    {
        int r = tid >> 1;                 // 0..255
        int h = tid & 1;                  // half of the row (100 f32 each)
        int edge = r & 127;
        bool isd = (r >= 128);
        int node = (isd ? dstp : srcp)[lbase + edge];
        float d0 = dinv[node];            // inter denom^-1 (cols < 97)
        float d1 = dinv[NN + node];       // intra denom^-1 (cols >= 97)
        const f32x4* rp = (const f32x4*)(rel + (size_t)node * RELSTR + h * 100);
        unsigned short* row = isd ? &d_lds[edge][0] : &s_lds[edge][0];
#pragma unroll
        for (int q = 0; q < 25; ++q) {
            f32x4 v = rp[q];
            int c = h * 100 + q * 4;
            float m0 = (c + 0 < DR) ? d0 : d1;
            float m1 = (c + 1 < DR) ? d0 : d1;
            float m2 = (c + 2 < DR) ? d0 : d1;
            float m3 = (c + 3 < DR) ? d0 : d1;
            unsigned u0 = (unsigned)f2bf(v[0] * m0) | ((unsigned)f2bf(v[1] * m1) << 16);
            unsigned u1 = (unsigned)f2bf(v[2] * m2) | ((unsigned)f2bf(v[3] * m3) << 16);
            *(unsigned*)&row[c] = u0;
            *(unsigned*)&row[c + 2] = u1;
        }
        if (isd && h) {   // zero cols 200..231 of d rows (K padding)
            short8 z = (short8)(short)0;
#pragma unroll
            for (int q = 0; q < 4; ++q)
                *(short8*)&row[200 + q * 8] = z;
        }
    }
    __syncthreads();

    int w = tid >> 6;                 // wave 0..7: owns edges [w*16, w*16+16)
    int lane = tid & 63;
    int er = (w << 4) + (lane & 15);  // A-frag row (edge within block)
    int lk = lane >> 4;               // k-element group
    const unsigned short* srow = &s_lds[er][0];
    const unsigned short* drow = &d_lds[er][0];

    f32x4 acc[NT];
    f32x4 zero = {0.f, 0.f, 0.f, 0.f};
#pragma unroll
    for (int t = 0; t < NT; ++t) acc[t] = zero;

    for (int i = 0; i < KI; ++i) {
        float sv = bf2f(srow[i]);
        const short8* bi = (const short8*)(Bpk + (size_t)(i * KS) * NT * 512) + lane;
#pragma unroll
        for (int ks = 0; ks < KS; ++ks) {
            u32x4 u = *(const u32x4*)(drow + ks * 32 + lk * 8);
            float d0 = __uint_as_float(u[0] << 16);
            float d1 = __uint_as_float(u[0] & 0xffff0000u);
            float d2 = __uint_as_float(u[1] << 16);
            float d3 = __uint_as_float(u[1] & 0xffff0000u);
            float d4 = __uint_as_float(u[2] << 16);
            float d5 = __uint_as_float(u[2] & 0xffff0000u);
            float d6 = __uint_as_float(u[3] << 16);
            float d7 = __uint_as_float(u[3] & 0xffff0000u);
            short8 af;
            af[0] = (short)f2bf(sv * d0);
            af[1] = (short)f2bf(sv * d1);
            af[2] = (short)f2bf(sv * d2);
            af[3] = (short)f2bf(sv * d3);
            af[4] = (short)f2bf(sv * d4);
            af[5] = (short)f2bf(sv * d5);
            af[6] = (short)f2bf(sv * d6);
            af[7] = (short)f2bf(sv * d7);
            const short8* bq = bi + ks * (NT * 64);
#pragma unroll
            for (int t = 0; t < NT; ++t) {
                short8 bv = bq[t * 64];
                acc[t] = __builtin_amdgcn_mfma_f32_16x16x32_bf16(af, bv, acc[t], 0, 0, 0);
            }
        }
    }

    // ---- epilogue: bias + sigmoid gate, out = e * (1 + sigmoid(gate)) ----
#pragma unroll
    for (int t = 0; t < NT; ++t) {
        int k = t * 16 + (lane & 15);
        if (k < DR) {
            float bb = bias[k];
#pragma unroll
            for (int r = 0; r < 4; ++r) {
                int edge = ebase + (w << 4) + lk * 4 + r;
                float g = acc[t][r] + bb;
                float sg = 1.f / (1.f + __expf(-g));
                int le = edge & (NE1 - 1);
                float ev = ep[(size_t)le * DR + k];
                out[(size_t)edge * DR + k] = ev * (1.f + sg);
            }
        }
    }
}

// ---------------------------------------------------------------------------
extern "C" void kernel_launch(void* const* d_in, const int* in_sizes, int n_in,
                              void* d_out, int out_size, void* d_ws, size_t ws_size,
                              hipStream_t stream) {
    (void)in_sizes; (void)n_in; (void)out_size; (void)ws_size;
    const float* nmat     = (const float*)d_in[0];
    const float* e_inter  = (const float*)d_in[1];
    const float* e_intra  = (const float*)d_in[2];
    const float* W_bl     = (const float*)d_in[3];   // [768,97]
    const float* W_bl1    = (const float*)d_in[4];   // [97,194,194]
    const float* b_bl1    = (const float*)d_in[5];   // [97]
    const int* src_inter  = (const int*)d_in[6];
    const int* dst_inter  = (const int*)d_in[7];
    const int* src_intra  = (const int*)d_in[8];
    const int* dst_intra  = (const int*)d_in[9];
    float* out = (float*)d_out;

    char* ws = (char*)d_ws;
    float* regA          = (float*)(ws + OFF_REL);   // proj first, then rel
    unsigned short* Bpk  = (unsigned short*)(ws + OFF_BPK);
    float* s_buf         = (float*)(ws + OFF_SBUF);
    unsigned* smax       = (unsigned*)(ws + OFF_SMAX);
    float* denom         = (float*)(ws + OFF_DEN);

    hipMemsetAsync(smax, 0, 524288, stream);
    hipMemsetAsync(denom, 0, 524288, stream);

    build_bpk<<<(KI * KS * NT * 64 + 255) / 256, 256, 0, stream>>>(W_bl1, Bpk);
    proj_kernel<<<NN / 32, 128, 0, stream>>>(nmat, W_bl, regA);
    score_kernel<<<NEG / 4, 256, 0, stream>>>(regA, e_inter, e_intra, dst_inter, dst_intra,
                                              s_buf, smax);
    // proj is dead now; region A becomes the rel accumulator [N,200] f32
    hipMemsetAsync(regA, 0, 52428800, stream);
    accum_kernel<<<NEG / 4, 256, 0, stream>>>(s_buf, e_inter, e_intra, dst_inter, dst_intra,
                                              smax, denom, regA);
    dinv_kernel<<<512, 256, 0, stream>>>(denom);
    gate_kernel<<<512, 512, 0, stream>>>(regA, denom, Bpk, b_bl1,
                                         src_inter, dst_inter, src_intra, dst_intra,
                                         e_inter, e_intra, out);
}